// Round 19
// baseline (293.965 us; speedup 1.0000x reference)
//
#include <hip/hip_runtime.h>
#include <hip/hip_bf16.h>
#include <math.h>

#define NTOK 4096   // B*S
#define DDIM 1024
#define HDIM 4096
#define EEXP 8
#define NPALLOC 10240

#define BM 128
#define BN 128
#define BK 64
#define GGRID 2560    // 8 xcd-chunks x 320 slots (covers max worklist)
#define C2BLKS 2048   // fused conv-w2 tail blocks

typedef __attribute__((ext_vector_type(8))) short short8;
typedef __attribute__((ext_vector_type(4))) short short4v;
typedef __attribute__((ext_vector_type(4))) float f32x4;

static __device__ __forceinline__ unsigned short f2bf(float f){
  unsigned int u = __float_as_uint(f);
  u += 0x7FFFu + ((u >> 16) & 1u);
  return (unsigned short)(u >> 16);
}
static __device__ __forceinline__ float bf2f(short s){
  return __uint_as_float(((unsigned int)(unsigned short)s) << 16);
}
static __device__ __forceinline__ void gload16(const void* g, void* l){
  __builtin_amdgcn_global_load_lds(
      (const __attribute__((address_space(1))) void*)g,
      (__attribute__((address_space(3))) void*)l, 16, 0, 0);
}

// convert one 16B-chunk of w (f32) -> wb (bf16, pre-swizzled within 8-chunk groups)
static __device__ __forceinline__ void conv_chunk(const float* __restrict__ w,
    short* __restrict__ wb, int klog2, size_t i){
  const int cshift = klog2 - 3;
  size_t n = i >> cshift;
  int c = (int)(i & ((1u << cshift) - 1u));
  int csw = (c & ~7) | ((c ^ (int)n) & 7);
  const float* src = w + (n << klog2) + (size_t)csw * 8;
  f32x4 a = ((const f32x4*)src)[0];
  f32x4 b = ((const f32x4*)src)[1];
  short8 o;
#pragma unroll
  for (int j = 0; j < 4; ++j){ o[j] = (short)f2bf(a[j]); o[j+4] = (short)f2bf(b[j]); }
  *(short8*)(wb + (n << klog2) + (size_t)c * 8) = o;
}

// ---- fused: blocks [0,4096) convert w1 (4 chunks/thread); [4096,5120) gate ----
// No global atomics (they were a 156us serial tail); counts rebuilt in scan_scatter.
__global__ __launch_bounds__(256) void conv1_gate_kernel(
    const float* __restrict__ w1, short* __restrict__ wb,
    const float* __restrict__ x, const float* __restrict__ gw,
    const float* __restrict__ gb, float* __restrict__ outF,
    short* __restrict__ xb, int2* __restrict__ te, float2* __restrict__ tw){
  if (blockIdx.x < 4096){
#pragma unroll
    for (int j = 0; j < 4; ++j)
      conv_chunk(w1, wb, 10, (size_t)blockIdx.x * 1024 + j * 256 + threadIdx.x);
    return;
  }
  const int t = (blockIdx.x - 4096) * 4 + (threadIdx.x >> 6);
  const int l = threadIdx.x & 63;
  const f32x4* xr = (const f32x4*)(x + (size_t)t * DDIM);
  f32x4 xv[4];
#pragma unroll
  for (int j = 0; j < 4; ++j) xv[j] = xr[l + 64*j];
#pragma unroll
  for (int j = 0; j < 4; ++j){
    short4v o;
#pragma unroll
    for (int q = 0; q < 4; ++q) o[q] = (short)f2bf(xv[j][q]);
    ((short4v*)(xb + (size_t)t * DDIM))[l + 64*j] = o;
  }
  float acc[EEXP];
#pragma unroll
  for (int e = 0; e < EEXP; ++e) acc[e] = 0.f;
#pragma unroll
  for (int j = 0; j < 4; ++j){
#pragma unroll
    for (int e = 0; e < EEXP; ++e){
      f32x4 gv = ((const f32x4*)(gw + (size_t)e*DDIM))[l + 64*j];
      acc[e] += xv[j][0]*gv[0] + xv[j][1]*gv[1] + xv[j][2]*gv[2] + xv[j][3]*gv[3];
    }
  }
#pragma unroll
  for (int e = 0; e < EEXP; ++e){
#pragma unroll
    for (int off = 32; off > 0; off >>= 1) acc[e] += __shfl_xor(acc[e], off);
  }
  if (l == 0){
    float lg[EEXP];
#pragma unroll
    for (int e = 0; e < EEXP; ++e) lg[e] = acc[e] + gb[e];
    int e0 = 0; float v0 = lg[0];
#pragma unroll
    for (int e = 1; e < EEXP; ++e) if (lg[e] > v0){ v0 = lg[e]; e0 = e; }
    int e1 = -1; float v1 = -1e30f;
#pragma unroll
    for (int e = 0; e < EEXP; ++e) if (e != e0 && lg[e] > v1){ v1 = lg[e]; e1 = e; }
    float r  = expf(v1 - v0);
    float w0 = 1.f / (1.f + r);
    float w1s = r / (1.f + r);
    outF[(size_t)NTOK*DDIM + 2*t    ] = (float)e0;
    outF[(size_t)NTOK*DDIM + 2*t + 1] = (float)e1;
    te[t] = make_int2(e0, e1);
    tw[t] = make_float2(w0, w1s);
  }
}

// meta: [0:8)cnt [8:16)offs [32:40)base1 [40:48)len1 [48:56)base2 [56:64)len2
//       [64:64+2560) wl1 | [2700:2700+2560) wl2.
// item: e | mt<<3 (7b) | n<<10 (5b) | ks<<15 (2b)
__global__ __launch_bounds__(256) void scan_scatter_kernel(int* __restrict__ meta,
    int* __restrict__ tokp, int* __restrict__ pidx, const int2* __restrict__ te,
    int ks2){
  __shared__ int tilesS[EEXP], b1S[EEXP + 1], b2S[EEXP + 1], cur[EEXP], hist[EEXP];
  for (int i = threadIdx.x; i < NPALLOC; i += 256) tokp[i] = 0;  // pad slots -> token 0
  if (threadIdx.x < EEXP){ cur[threadIdx.x] = 0; hist[threadIdx.x] = 0; }
  __syncthreads();
  for (int t = threadIdx.x; t < NTOK; t += 256){   // LDS histogram (fast atomics)
    int2 e = te[t];
    atomicAdd(&hist[e.x], 1);
    atomicAdd(&hist[e.y], 1);
  }
  __syncthreads();
  if (threadIdx.x == 0){
    int s = 0, t1 = 0, t2 = 0;
    for (int e = 0; e < EEXP; ++e){
      int c = hist[e];
      meta[e] = c;
      meta[8+e] = s;
      int tl = (c + 127) >> 7;
      tilesS[e] = tl;
      b1S[e] = t1; t1 += tl * (HDIM / BN);       // 32 n-tiles
      b2S[e] = t2; t2 += tl * (DDIM / BN) * ks2; // 8 n-tiles x ks
      s += (c + 127) & ~127;
    }
    b1S[EEXP] = t1; b2S[EEXP] = t2;
    int q = t1 >> 3, r = t1 & 7;
    for (int x = 0; x < 8; ++x){ meta[32+x] = x*q + (x<r?x:r); meta[40+x] = q + (x<r?1:0); }
    q = t2 >> 3; r = t2 & 7;
    for (int x = 0; x < 8; ++x){ meta[48+x] = x*q + (x<r?x:r); meta[56+x] = q + (x<r?1:0); }
  }
  __syncthreads();
  const int n1 = b1S[EEXP], n2 = b2S[EEXP];
  for (int i = threadIdx.x; i < n1; i += 256){   // e-contig, n outer, m inner
    int e = 0;
#pragma unroll
    for (int k = 0; k < EEXP - 1; ++k) if (i >= b1S[k+1]) e = k + 1;
    const int loc = i - b1S[e], tl = tilesS[e];
    const int n = loc / tl, mt = loc - n * tl;
    meta[64 + i] = e | (mt << 3) | (n << 10);
  }
  for (int i = threadIdx.x; i < n2; i += 256){   // e-contig, ks, n, m inner
    int e = 0;
#pragma unroll
    for (int k = 0; k < EEXP - 1; ++k) if (i >= b2S[k+1]) e = k + 1;
    const int loc = i - b2S[e], tl = tilesS[e];
    const int k8 = loc / ((DDIM / BN) * tl);
    const int rem = loc - k8 * (DDIM / BN) * tl;
    const int n = rem / tl, mt = rem - n * tl;
    meta[2700 + i] = e | (mt << 3) | (n << 10) | (k8 << 15);
  }
  for (int t = threadIdx.x; t < NTOK; t += 256){
    int2 e = te[t];
    int p0 = meta[8+e.x] + atomicAdd(&cur[e.x], 1);
    tokp[p0] = t; pidx[2*t] = p0;
    int p1 = meta[8+e.y] + atomicAdd(&cur[e.y], 1);
    tokp[p1] = t; pidx[2*t+1] = p1;
  }
}

// ---- grouped GEMM, m97 structure: 128x128xBK64, 4 waves, 32KB LDS single-buffered,
// 2 syncthreads/K-step, 3 blocks/CU. This round's single change vs R15: T5 setprio
// around the MFMA bursts (independent-block regime, m191 mechanism).
// PHASE 1 (+conv-w2 tail): h = GELU(gather(xb) @ w1b^T + b1), pre-swizzled stores
// PHASE 2: y[ks] = h @ w2b^T (K-split, unweighted bf16 partials)
template<int PHASE, int KDIM, int NDIM, int KSPLIT>
__global__ __launch_bounds__(256, 3) void moe_gemm(
    const short* __restrict__ Ab, const short* __restrict__ Wb,
    const float* __restrict__ bias, const int* __restrict__ meta,
    const int* __restrict__ tokp,
    short* __restrict__ O0, short* __restrict__ O1,
    short* __restrict__ O2, short* __restrict__ O3,
    const float* __restrict__ wsrc, short* __restrict__ wdst, int nconv){
  if (PHASE == 1 && (int)blockIdx.x >= GGRID){
    if (nconv){
#pragma unroll
      for (int j = 0; j < 8; ++j)
        conv_chunk(wsrc, wdst, 12, (size_t)(blockIdx.x - GGRID) * 2048 + j * 256 + threadIdx.x);
    }
    return;
  }
  constexpr int KLEN = KDIM / KSPLIT;
  constexpr int NK = KLEN / BK;
  const int xcd  = blockIdx.x & 7;
  const int slot = blockIdx.x >> 3;
  if (slot >= meta[(PHASE == 1 ? 40 : 56) + xcd]) return;
  const int item = meta[(PHASE == 1 ? 64 : 2700)
                        + meta[(PHASE == 1 ? 32 : 48) + xcd] + slot];
  const int e  = item & 7;
  const int m0 = ((item >> 3) & 127) << 7;
  const int n0 = ((item >> 10) & 31) * BN;
  const int ks = (item >> 15) & 3;
  const int cnt = meta[e];
  const int off = meta[8 + e];
  const int mrows = min(BM, cnt - m0);
  const int kbase = ks * KLEN;
  short* O = (ks == 0) ? O0 : (ks == 1) ? O1 : (ks == 2) ? O2 : O3;

  __shared__ __align__(16) short SMEM[2][BM * BK];   // As | Bs = 32 KB

  const int tid  = threadIdx.x;
  const int lane = tid & 63;
  const int wid  = tid >> 6;   // 4 waves
  const int wr   = wid >> 1;   // 0..1 -> 64 rows
  const int wc   = wid & 1;    // 0..1 -> 64 cols

  const short* wE = Wb + (size_t)e * NDIM * KDIM;
  size_t aSrc[4], bSrc[4]; int ldsOff[4];
#pragma unroll
  for (int s = 0; s < 4; ++s){
    const int rb = wid * 8 + s * 32;            // wave-uniform base row
    ldsOff[s] = rb * BK;                        // shorts; HW adds lane*16B
    const int r = rb + (lane >> 3);
    size_t grow; int acol;
    if (PHASE == 1){
      grow = (size_t)tokp[off + m0 + r];        // fused gather (per-lane global addr)
      acol = (((lane & 7) ^ (r & 7)) << 3);     // source-swizzle (xb linear)
    } else {
      grow = (size_t)(off + m0 + r);            // h compact, content pre-swizzled
      acol = (lane & 7) << 3;
    }
    aSrc[s] = grow * KDIM + kbase + acol;
    bSrc[s] = (size_t)(n0 + r) * KDIM + kbase + ((lane & 7) << 3);  // wb pre-swizzled
  }

  f32x4 acc[4][4];
#pragma unroll
  for (int i = 0; i < 4; ++i)
#pragma unroll
    for (int j = 0; j < 4; ++j) acc[i][j] = (f32x4){0.f, 0.f, 0.f, 0.f};

  for (int t = 0; t < NK; ++t){
    const int k0 = t * BK;
#pragma unroll
    for (int s = 0; s < 4; ++s) gload16(Ab + aSrc[s] + k0, &SMEM[0][ldsOff[s]]);
#pragma unroll
    for (int s = 0; s < 4; ++s) gload16(wE + bSrc[s] + k0, &SMEM[1][ldsOff[s]]);
    __syncthreads();                 // vmcnt(0)+barrier: tile staged (m97 structure)
    short8 bf[4][2];
#pragma unroll
    for (int j = 0; j < 4; ++j){
      const int rB = wc * 64 + j * 16 + (lane & 15);
#pragma unroll
      for (int kk = 0; kk < 2; ++kk){
        const int bc = kk * 64 + (lane >> 4) * 16;
        bf[j][kk] = *(const short8*)&SMEM[1][rB * BK + ((bc ^ ((rB & 7) << 4)) >> 1)];
      }
    }
#pragma unroll
    for (int i = 0; i < 4; ++i){
      const int rA = wr * 64 + i * 16 + (lane & 15);
      short8 af[2];
#pragma unroll
      for (int kk = 0; kk < 2; ++kk){
        const int bc = kk * 64 + (lane >> 4) * 16;
        af[kk] = *(const short8*)&SMEM[0][rA * BK + ((bc ^ ((rA & 7) << 4)) >> 1)];
      }
      __builtin_amdgcn_s_setprio(1);   // T5: favor MFMA burst over other blocks' staging
#pragma unroll
      for (int j = 0; j < 4; ++j)
#pragma unroll
        for (int kk = 0; kk < 2; ++kk)
          acc[i][j] = __builtin_amdgcn_mfma_f32_16x16x32_bf16(af[kk], bf[j][kk], acc[i][j], 0, 0, 0);
      __builtin_amdgcn_s_setprio(0);
    }
    __syncthreads();                 // reads retired before next overwrite
  }

  // ---- epilogue: acc -> LDS T[128][128] bf16 (swizzled) -> coalesced stores ----
  short* T = &SMEM[0][0];
#pragma unroll
  for (int j = 0; j < 4; ++j){
    const int n = n0 + wc * 64 + j * 16 + (lane & 15);
    const float bv = (PHASE == 1) ? bias[(size_t)e * NDIM + n] : 0.f;
#pragma unroll
    for (int i = 0; i < 4; ++i){
#pragma unroll
      for (int q = 0; q < 4; ++q){
        const int r = wr * 64 + i * 16 + (lane >> 4) * 4 + q;
        const int c = wc * 64 + j * 16 + (lane & 15);
        float v = acc[i][j][q];
        if (PHASE == 1){
          v += bv;
          float u2 = v * (1.5957691216057308f + 0.07135481627014317f * v * v);
          v = v / (1.f + __expf(-u2));       // tanh-GELU (err ~1e-3 << 0.14)
        }
        T[r * BN + (c ^ ((r & 7) << 3))] = (short)f2bf(v);
      }
    }
  }
  __syncthreads();
  {
    const int r = tid >> 1;                  // 128 rows, 2 threads/row
    const int key = r & 7;
    const size_t rowb = (size_t)(off + m0 + r) * NDIM + n0;
#pragma unroll
    for (int c8 = 0; c8 < 8; ++c8){
      const int ci = (tid & 1) * 8 + c8;     // 16 chunks/row
      const int pc = (ci & ~7) | ((ci ^ key) & 7);
      short8 v = *(const short8*)&T[r * BN + pc * 8];
      const int gcc = (PHASE == 1) ? pc : ci;   // P1 pre-swizzled; P2 linear
      if (r < mrows) *(short8*)&O[rowb + (size_t)gcc * 8] = v;
    }
  }
}

__global__ __launch_bounds__(512) void conv2_kernel(const float* __restrict__ w2,
    short* __restrict__ wb){
#pragma unroll
  for (int j = 0; j < 4; ++j)
    conv_chunk(w2, wb, 12, (size_t)blockIdx.x * 2048 + j * 512 + threadIdx.x);
}

// ---- combine: out[t] = w0*(sum_ks y[ks][p0]+b2[e0]) + w1*(sum_ks y[ks][p1]+b2[e1]) ----
template<int KS>
__global__ __launch_bounds__(256) void combine_kernel(
    const short* __restrict__ y0, const short* __restrict__ y1,
    const short* __restrict__ y2, const short* __restrict__ y3,
    const int2* __restrict__ te, const float2* __restrict__ tw,
    const int* __restrict__ pidx, const float* __restrict__ b2,
    float* __restrict__ outF){
  const int t = blockIdx.x;
  const int d = threadIdx.x * 4;
  int2 e = te[t]; float2 w = tw[t];
  int p0 = pidx[2*t], p1 = pidx[2*t+1];
  const short* ys[4] = {y0, y1, y2, y3};
  float s0[4] = {0.f,0.f,0.f,0.f}, s1[4] = {0.f,0.f,0.f,0.f};
#pragma unroll
  for (int k = 0; k < KS; ++k){
    short4v a = *(const short4v*)&ys[k][(size_t)p0 * DDIM + d];
    short4v c = *(const short4v*)&ys[k][(size_t)p1 * DDIM + d];
#pragma unroll
    for (int q = 0; q < 4; ++q){ s0[q] += bf2f(a[q]); s1[q] += bf2f(c[q]); }
  }
  f32x4 b0 = *(const f32x4*)&b2[(size_t)e.x * DDIM + d];
  f32x4 b1 = *(const f32x4*)&b2[(size_t)e.y * DDIM + d];
  f32x4 o;
#pragma unroll
  for (int q = 0; q < 4; ++q)
    o[q] = w.x * (s0[q] + b0[q]) + w.y * (s1[q] + b1[q]);
  *(f32x4*)&outF[(size_t)t * DDIM + d] = o;
}

extern "C" void kernel_launch(void* const* d_in, const int* in_sizes, int n_in,
                              void* d_out, int out_size, void* d_ws, size_t ws_size,
                              hipStream_t stream){
  const float* x  = (const float*)d_in[0];
  const float* gw = (const float*)d_in[1];
  const float* gb = (const float*)d_in[2];
  const float* w1 = (const float*)d_in[3];
  const float* b1 = (const float*)d_in[4];
  const float* w2 = (const float*)d_in[5];
  const float* b2 = (const float*)d_in[6];
  float* outF = (float*)d_out;

  char* p = (char*)d_ws;
  short* xb = (short*)p;  p += (size_t)NTOK * DDIM * 2;          // 8.4 MB
  short* h  = (short*)p;  p += (size_t)NPALLOC * HDIM * 2;       // 83.9 MB
  short* wb = (short*)p;  p += (size_t)EEXP * HDIM * DDIM * 2;   // 67.1 MB (w1b; later y2/y3)
  short* y0 = (short*)p;  p += (size_t)NPALLOC * DDIM * 2;       // 21 MB
  short* y1 = (short*)p;  p += (size_t)NPALLOC * DDIM * 2;       // 21 MB
  int*   tokp = (int*)p;  p += (size_t)NPALLOC * 4;
  int*   pidx = (int*)p;  p += (size_t)2 * NTOK * 4;
  int2*  te   = (int2*)p; p += (size_t)NTOK * 8;
  float2* tw  = (float2*)p; p += (size_t)NTOK * 8;
  int* meta = (int*)p;    p += 8192 * 4;
  short* wb2 = (short*)p; p += (size_t)EEXP * HDIM * DDIM * 2;   // 67.1 MB (w2b, optional)
  const bool dualW = ws_size >= (size_t)(p - (char*)d_ws);
  short* y2 = wb;                          // w1b dead during GEMM2 (dualW path)
  short* y3 = wb + (size_t)NPALLOC * DDIM;

  conv1_gate_kernel<<<4096 + NTOK / 4, 256, 0, stream>>>(
      w1, wb, x, gw, gb, outF, xb, te, tw);
  scan_scatter_kernel<<<1, 256, 0, stream>>>(meta, tokp, pidx, te, dualW ? 4 : 2);
  if (dualW){
    moe_gemm<1, DDIM, HDIM, 1><<<GGRID + C2BLKS, 256, 0, stream>>>(
        xb, wb, b1, meta, tokp, h, h, h, h, w2, wb2, 1);
    moe_gemm<2, HDIM, DDIM, 4><<<GGRID, 256, 0, stream>>>(
        h, wb2, nullptr, meta, tokp, y0, y1, y2, y3, nullptr, nullptr, 0);
    combine_kernel<4><<<NTOK, 256, 0, stream>>>(y0, y1, y2, y3, te, tw, pidx, b2, outF);
  } else {
    moe_gemm<1, DDIM, HDIM, 1><<<GGRID, 256, 0, stream>>>(
        xb, wb, b1, meta, tokp, h, h, h, h, nullptr, nullptr, 0);
    conv2_kernel<<<C2BLKS, 512, 0, stream>>>(w2, wb);
    moe_gemm<2, HDIM, DDIM, 2><<<GGRID, 256, 0, stream>>>(
        h, wb, nullptr, meta, tokp, y0, y1, y0, y1, nullptr, nullptr, 0);
    combine_kernel<2><<<NTOK, 256, 0, stream>>>(y0, y1, y0, y1, te, tw, pidx, b2, outF);
  }
}

// Round 20
// 290.124 us; speedup vs baseline: 1.0132x; 1.0132x over previous
//
#include <hip/hip_runtime.h>
#include <hip/hip_bf16.h>
#include <math.h>

#define NTOK 4096   // B*S
#define DDIM 1024
#define HDIM 4096
#define EEXP 8
#define NPALLOC 10240

#define BM 128
#define BN 128
#define BK 64
#define GGRID 2560    // 8 xcd-chunks x 320 slots (covers max worklist)
#define C2BLKS 2048   // fused conv-w2 tail blocks

typedef __attribute__((ext_vector_type(8))) short short8;
typedef __attribute__((ext_vector_type(4))) short short4v;
typedef __attribute__((ext_vector_type(4))) float f32x4;

static __device__ __forceinline__ unsigned short f2bf(float f){
  unsigned int u = __float_as_uint(f);
  u += 0x7FFFu + ((u >> 16) & 1u);
  return (unsigned short)(u >> 16);
}
static __device__ __forceinline__ float bf2f(short s){
  return __uint_as_float(((unsigned int)(unsigned short)s) << 16);
}
static __device__ __forceinline__ void gload16(const void* g, void* l){
  __builtin_amdgcn_global_load_lds(
      (const __attribute__((address_space(1))) void*)g,
      (__attribute__((address_space(3))) void*)l, 16, 0, 0);
}

// convert one 16B-chunk of w (f32) -> wb (bf16, pre-swizzled within 8-chunk groups)
static __device__ __forceinline__ void conv_chunk(const float* __restrict__ w,
    short* __restrict__ wb, int klog2, size_t i){
  const int cshift = klog2 - 3;
  size_t n = i >> cshift;
  int c = (int)(i & ((1u << cshift) - 1u));
  int csw = (c & ~7) | ((c ^ (int)n) & 7);
  const float* src = w + (n << klog2) + (size_t)csw * 8;
  f32x4 a = ((const f32x4*)src)[0];
  f32x4 b = ((const f32x4*)src)[1];
  short8 o;
#pragma unroll
  for (int j = 0; j < 4; ++j){ o[j] = (short)f2bf(a[j]); o[j+4] = (short)f2bf(b[j]); }
  *(short8*)(wb + (n << klog2) + (size_t)c * 8) = o;
}

// ---- fused: blocks [0,4096) convert w1 (4 chunks/thread); [4096,5120) gate ----
// No global atomics (they were a 156us serial tail); counts rebuilt in scan_scatter.
__global__ __launch_bounds__(256) void conv1_gate_kernel(
    const float* __restrict__ w1, short* __restrict__ wb,
    const float* __restrict__ x, const float* __restrict__ gw,
    const float* __restrict__ gb, float* __restrict__ outF,
    short* __restrict__ xb, int2* __restrict__ te, float2* __restrict__ tw){
  if (blockIdx.x < 4096){
#pragma unroll
    for (int j = 0; j < 4; ++j)
      conv_chunk(w1, wb, 10, (size_t)blockIdx.x * 1024 + j * 256 + threadIdx.x);
    return;
  }
  const int t = (blockIdx.x - 4096) * 4 + (threadIdx.x >> 6);
  const int l = threadIdx.x & 63;
  const f32x4* xr = (const f32x4*)(x + (size_t)t * DDIM);
  f32x4 xv[4];
#pragma unroll
  for (int j = 0; j < 4; ++j) xv[j] = xr[l + 64*j];
#pragma unroll
  for (int j = 0; j < 4; ++j){
    short4v o;
#pragma unroll
    for (int q = 0; q < 4; ++q) o[q] = (short)f2bf(xv[j][q]);
    ((short4v*)(xb + (size_t)t * DDIM))[l + 64*j] = o;
  }
  float acc[EEXP];
#pragma unroll
  for (int e = 0; e < EEXP; ++e) acc[e] = 0.f;
#pragma unroll
  for (int j = 0; j < 4; ++j){
#pragma unroll
    for (int e = 0; e < EEXP; ++e){
      f32x4 gv = ((const f32x4*)(gw + (size_t)e*DDIM))[l + 64*j];
      acc[e] += xv[j][0]*gv[0] + xv[j][1]*gv[1] + xv[j][2]*gv[2] + xv[j][3]*gv[3];
    }
  }
#pragma unroll
  for (int e = 0; e < EEXP; ++e){
#pragma unroll
    for (int off = 32; off > 0; off >>= 1) acc[e] += __shfl_xor(acc[e], off);
  }
  if (l == 0){
    float lg[EEXP];
#pragma unroll
    for (int e = 0; e < EEXP; ++e) lg[e] = acc[e] + gb[e];
    int e0 = 0; float v0 = lg[0];
#pragma unroll
    for (int e = 1; e < EEXP; ++e) if (lg[e] > v0){ v0 = lg[e]; e0 = e; }
    int e1 = -1; float v1 = -1e30f;
#pragma unroll
    for (int e = 0; e < EEXP; ++e) if (e != e0 && lg[e] > v1){ v1 = lg[e]; e1 = e; }
    float r  = expf(v1 - v0);
    float w0 = 1.f / (1.f + r);
    float w1s = r / (1.f + r);
    outF[(size_t)NTOK*DDIM + 2*t    ] = (float)e0;
    outF[(size_t)NTOK*DDIM + 2*t + 1] = (float)e1;
    te[t] = make_int2(e0, e1);
    tw[t] = make_float2(w0, w1s);
  }
}

// meta: [0:8)cnt [8:16)offs [32:40)base1 [40:48)len1 [48:56)base2 [56:64)len2
//       [64:64+2560) wl1 | [2700:2700+2560) wl2.
// item: e | mt<<3 (7b) | n<<10 (5b) | ks<<15 (2b)
__global__ __launch_bounds__(256) void scan_scatter_kernel(int* __restrict__ meta,
    int* __restrict__ tokp, int* __restrict__ pidx, const int2* __restrict__ te,
    int ks2){
  __shared__ int tilesS[EEXP], b1S[EEXP + 1], b2S[EEXP + 1], cur[EEXP], hist[EEXP];
  for (int i = threadIdx.x; i < NPALLOC; i += 256) tokp[i] = 0;  // pad slots -> token 0
  if (threadIdx.x < EEXP){ cur[threadIdx.x] = 0; hist[threadIdx.x] = 0; }
  __syncthreads();
  for (int t = threadIdx.x; t < NTOK; t += 256){   // LDS histogram (fast atomics)
    int2 e = te[t];
    atomicAdd(&hist[e.x], 1);
    atomicAdd(&hist[e.y], 1);
  }
  __syncthreads();
  if (threadIdx.x == 0){
    int s = 0, t1 = 0, t2 = 0;
    for (int e = 0; e < EEXP; ++e){
      int c = hist[e];
      meta[e] = c;
      meta[8+e] = s;
      int tl = (c + 127) >> 7;
      tilesS[e] = tl;
      b1S[e] = t1; t1 += tl * (HDIM / BN);       // 32 n-tiles
      b2S[e] = t2; t2 += tl * (DDIM / BN) * ks2; // 8 n-tiles x ks
      s += (c + 127) & ~127;
    }
    b1S[EEXP] = t1; b2S[EEXP] = t2;
    int q = t1 >> 3, r = t1 & 7;
    for (int x = 0; x < 8; ++x){ meta[32+x] = x*q + (x<r?x:r); meta[40+x] = q + (x<r?1:0); }
    q = t2 >> 3; r = t2 & 7;
    for (int x = 0; x < 8; ++x){ meta[48+x] = x*q + (x<r?x:r); meta[56+x] = q + (x<r?1:0); }
  }
  __syncthreads();
  const int n1 = b1S[EEXP], n2 = b2S[EEXP];
  for (int i = threadIdx.x; i < n1; i += 256){   // e-contig, n outer, m inner
    int e = 0;
#pragma unroll
    for (int k = 0; k < EEXP - 1; ++k) if (i >= b1S[k+1]) e = k + 1;
    const int loc = i - b1S[e], tl = tilesS[e];
    const int n = loc / tl, mt = loc - n * tl;
    meta[64 + i] = e | (mt << 3) | (n << 10);
  }
  for (int i = threadIdx.x; i < n2; i += 256){   // e-contig, ks, n, m inner
    int e = 0;
#pragma unroll
    for (int k = 0; k < EEXP - 1; ++k) if (i >= b2S[k+1]) e = k + 1;
    const int loc = i - b2S[e], tl = tilesS[e];
    const int k8 = loc / ((DDIM / BN) * tl);
    const int rem = loc - k8 * (DDIM / BN) * tl;
    const int n = rem / tl, mt = rem - n * tl;
    meta[2700 + i] = e | (mt << 3) | (n << 10) | (k8 << 15);
  }
  for (int t = threadIdx.x; t < NTOK; t += 256){
    int2 e = te[t];
    int p0 = meta[8+e.x] + atomicAdd(&cur[e.x], 1);
    tokp[p0] = t; pidx[2*t] = p0;
    int p1 = meta[8+e.y] + atomicAdd(&cur[e.y], 1);
    tokp[p1] = t; pidx[2*t+1] = p1;
  }
}

// ---- grouped GEMM, m97 structure: 128x128xBK64, 4 waves, 32KB LDS single-buffered,
// 2 syncthreads/K-step, 3 blocks/CU (inter-block wave overlap hides the drains).
// PHASE 1 (+conv-w2 tail): h = GELU(gather(xb) @ w1b^T + b1), pre-swizzled stores
// PHASE 2: y[ks] = h @ w2b^T (K-split, unweighted bf16 partials)
template<int PHASE, int KDIM, int NDIM, int KSPLIT>
__global__ __launch_bounds__(256, 3) void moe_gemm(
    const short* __restrict__ Ab, const short* __restrict__ Wb,
    const float* __restrict__ bias, const int* __restrict__ meta,
    const int* __restrict__ tokp,
    short* __restrict__ O0, short* __restrict__ O1,
    short* __restrict__ O2, short* __restrict__ O3,
    const float* __restrict__ wsrc, short* __restrict__ wdst, int nconv){
  if (PHASE == 1 && (int)blockIdx.x >= GGRID){
    if (nconv){
#pragma unroll
      for (int j = 0; j < 8; ++j)
        conv_chunk(wsrc, wdst, 12, (size_t)(blockIdx.x - GGRID) * 2048 + j * 256 + threadIdx.x);
    }
    return;
  }
  constexpr int KLEN = KDIM / KSPLIT;
  constexpr int NK = KLEN / BK;
  const int xcd  = blockIdx.x & 7;
  const int slot = blockIdx.x >> 3;
  if (slot >= meta[(PHASE == 1 ? 40 : 56) + xcd]) return;
  const int item = meta[(PHASE == 1 ? 64 : 2700)
                        + meta[(PHASE == 1 ? 32 : 48) + xcd] + slot];
  const int e  = item & 7;
  const int m0 = ((item >> 3) & 127) << 7;
  const int n0 = ((item >> 10) & 31) * BN;
  const int ks = (item >> 15) & 3;
  const int cnt = meta[e];
  const int off = meta[8 + e];
  const int mrows = min(BM, cnt - m0);
  const int kbase = ks * KLEN;
  short* O = (ks == 0) ? O0 : (ks == 1) ? O1 : (ks == 2) ? O2 : O3;

  __shared__ __align__(16) short SMEM[2][BM * BK];   // As | Bs = 32 KB

  const int tid  = threadIdx.x;
  const int lane = tid & 63;
  const int wid  = tid >> 6;   // 4 waves
  const int wr   = wid >> 1;   // 0..1 -> 64 rows
  const int wc   = wid & 1;    // 0..1 -> 64 cols

  const short* wE = Wb + (size_t)e * NDIM * KDIM;
  size_t aSrc[4], bSrc[4]; int ldsOff[4];
#pragma unroll
  for (int s = 0; s < 4; ++s){
    const int rb = wid * 8 + s * 32;            // wave-uniform base row
    ldsOff[s] = rb * BK;                        // shorts; HW adds lane*16B
    const int r = rb + (lane >> 3);
    size_t grow; int acol;
    if (PHASE == 1){
      grow = (size_t)tokp[off + m0 + r];        // fused gather (per-lane global addr)
      acol = (((lane & 7) ^ (r & 7)) << 3);     // source-swizzle (xb linear)
    } else {
      grow = (size_t)(off + m0 + r);            // h compact, content pre-swizzled
      acol = (lane & 7) << 3;
    }
    aSrc[s] = grow * KDIM + kbase + acol;
    bSrc[s] = (size_t)(n0 + r) * KDIM + kbase + ((lane & 7) << 3);  // wb pre-swizzled
  }

  f32x4 acc[4][4];
#pragma unroll
  for (int i = 0; i < 4; ++i)
#pragma unroll
    for (int j = 0; j < 4; ++j) acc[i][j] = (f32x4){0.f, 0.f, 0.f, 0.f};

  for (int t = 0; t < NK; ++t){
    const int k0 = t * BK;
#pragma unroll
    for (int s = 0; s < 4; ++s) gload16(Ab + aSrc[s] + k0, &SMEM[0][ldsOff[s]]);
#pragma unroll
    for (int s = 0; s < 4; ++s) gload16(wE + bSrc[s] + k0, &SMEM[1][ldsOff[s]]);
    __syncthreads();                 // vmcnt(0)+barrier: tile staged (m97 structure)
    short8 bf[4][2];
#pragma unroll
    for (int j = 0; j < 4; ++j){
      const int rB = wc * 64 + j * 16 + (lane & 15);
#pragma unroll
      for (int kk = 0; kk < 2; ++kk){
        const int bc = kk * 64 + (lane >> 4) * 16;
        bf[j][kk] = *(const short8*)&SMEM[1][rB * BK + ((bc ^ ((rB & 7) << 4)) >> 1)];
      }
    }
#pragma unroll
    for (int i = 0; i < 4; ++i){
      const int rA = wr * 64 + i * 16 + (lane & 15);
      short8 af[2];
#pragma unroll
      for (int kk = 0; kk < 2; ++kk){
        const int bc = kk * 64 + (lane >> 4) * 16;
        af[kk] = *(const short8*)&SMEM[0][rA * BK + ((bc ^ ((rA & 7) << 4)) >> 1)];
      }
#pragma unroll
      for (int j = 0; j < 4; ++j)
#pragma unroll
        for (int kk = 0; kk < 2; ++kk)
          acc[i][j] = __builtin_amdgcn_mfma_f32_16x16x32_bf16(af[kk], bf[j][kk], acc[i][j], 0, 0, 0);
    }
    __syncthreads();                 // reads retired before next overwrite
  }

  // ---- epilogue: acc -> LDS T[128][128] bf16 (swizzled) -> coalesced stores ----
  short* T = &SMEM[0][0];
#pragma unroll
  for (int j = 0; j < 4; ++j){
    const int n = n0 + wc * 64 + j * 16 + (lane & 15);
    const float bv = (PHASE == 1) ? bias[(size_t)e * NDIM + n] : 0.f;
#pragma unroll
    for (int i = 0; i < 4; ++i){
#pragma unroll
      for (int q = 0; q < 4; ++q){
        const int r = wr * 64 + i * 16 + (lane >> 4) * 4 + q;
        const int c = wc * 64 + j * 16 + (lane & 15);
        float v = acc[i][j][q];
        if (PHASE == 1){
          v += bv;
          float u2 = v * (1.5957691216057308f + 0.07135481627014317f * v * v);
          v = v / (1.f + __expf(-u2));       // tanh-GELU (err ~1e-3 << 0.14)
        }
        T[r * BN + (c ^ ((r & 7) << 3))] = (short)f2bf(v);
      }
    }
  }
  __syncthreads();
  {
    const int r = tid >> 1;                  // 128 rows, 2 threads/row
    const int key = r & 7;
    const size_t rowb = (size_t)(off + m0 + r) * NDIM + n0;
#pragma unroll
    for (int c8 = 0; c8 < 8; ++c8){
      const int ci = (tid & 1) * 8 + c8;     // 16 chunks/row
      const int pc = (ci & ~7) | ((ci ^ key) & 7);
      short8 v = *(const short8*)&T[r * BN + pc * 8];
      const int gcc = (PHASE == 1) ? pc : ci;   // P1 pre-swizzled; P2 linear
      if (r < mrows) *(short8*)&O[rowb + (size_t)gcc * 8] = v;
    }
  }
}

__global__ __launch_bounds__(512) void conv2_kernel(const float* __restrict__ w2,
    short* __restrict__ wb){
#pragma unroll
  for (int j = 0; j < 4; ++j)
    conv_chunk(w2, wb, 12, (size_t)blockIdx.x * 2048 + j * 512 + threadIdx.x);
}

// ---- combine: out[t] = w0*(sum_ks y[ks][p0]+b2[e0]) + w1*(sum_ks y[ks][p1]+b2[e1]) ----
template<int KS>
__global__ __launch_bounds__(256) void combine_kernel(
    const short* __restrict__ y0, const short* __restrict__ y1,
    const short* __restrict__ y2, const short* __restrict__ y3,
    const int2* __restrict__ te, const float2* __restrict__ tw,
    const int* __restrict__ pidx, const float* __restrict__ b2,
    float* __restrict__ outF){
  const int t = blockIdx.x;
  const int d = threadIdx.x * 4;
  int2 e = te[t]; float2 w = tw[t];
  int p0 = pidx[2*t], p1 = pidx[2*t+1];
  const short* ys[4] = {y0, y1, y2, y3};
  float s0[4] = {0.f,0.f,0.f,0.f}, s1[4] = {0.f,0.f,0.f,0.f};
#pragma unroll
  for (int k = 0; k < KS; ++k){
    short4v a = *(const short4v*)&ys[k][(size_t)p0 * DDIM + d];
    short4v c = *(const short4v*)&ys[k][(size_t)p1 * DDIM + d];
#pragma unroll
    for (int q = 0; q < 4; ++q){ s0[q] += bf2f(a[q]); s1[q] += bf2f(c[q]); }
  }
  f32x4 b0 = *(const f32x4*)&b2[(size_t)e.x * DDIM + d];
  f32x4 b1 = *(const f32x4*)&b2[(size_t)e.y * DDIM + d];
  f32x4 o;
#pragma unroll
  for (int q = 0; q < 4; ++q)
    o[q] = w.x * (s0[q] + b0[q]) + w.y * (s1[q] + b1[q]);
  *(f32x4*)&outF[(size_t)t * DDIM + d] = o;
}

extern "C" void kernel_launch(void* const* d_in, const int* in_sizes, int n_in,
                              void* d_out, int out_size, void* d_ws, size_t ws_size,
                              hipStream_t stream){
  const float* x  = (const float*)d_in[0];
  const float* gw = (const float*)d_in[1];
  const float* gb = (const float*)d_in[2];
  const float* w1 = (const float*)d_in[3];
  const float* b1 = (const float*)d_in[4];
  const float* w2 = (const float*)d_in[5];
  const float* b2 = (const float*)d_in[6];
  float* outF = (float*)d_out;

  char* p = (char*)d_ws;
  short* xb = (short*)p;  p += (size_t)NTOK * DDIM * 2;          // 8.4 MB
  short* h  = (short*)p;  p += (size_t)NPALLOC * HDIM * 2;       // 83.9 MB
  short* wb = (short*)p;  p += (size_t)EEXP * HDIM * DDIM * 2;   // 67.1 MB (w1b; later y2/y3)
  short* y0 = (short*)p;  p += (size_t)NPALLOC * DDIM * 2;       // 21 MB
  short* y1 = (short*)p;  p += (size_t)NPALLOC * DDIM * 2;       // 21 MB
  int*   tokp = (int*)p;  p += (size_t)NPALLOC * 4;
  int*   pidx = (int*)p;  p += (size_t)2 * NTOK * 4;
  int2*  te   = (int2*)p; p += (size_t)NTOK * 8;
  float2* tw  = (float2*)p; p += (size_t)NTOK * 8;
  int* meta = (int*)p;    p += 8192 * 4;
  short* wb2 = (short*)p; p += (size_t)EEXP * HDIM * DDIM * 2;   // 67.1 MB (w2b, optional)
  const bool dualW = ws_size >= (size_t)(p - (char*)d_ws);
  short* y2 = wb;                          // w1b dead during GEMM2 (dualW path)
  short* y3 = wb + (size_t)NPALLOC * DDIM;

  conv1_gate_kernel<<<4096 + NTOK / 4, 256, 0, stream>>>(
      w1, wb, x, gw, gb, outF, xb, te, tw);
  scan_scatter_kernel<<<1, 256, 0, stream>>>(meta, tokp, pidx, te, dualW ? 4 : 2);
  if (dualW){
    moe_gemm<1, DDIM, HDIM, 1><<<GGRID + C2BLKS, 256, 0, stream>>>(
        xb, wb, b1, meta, tokp, h, h, h, h, w2, wb2, 1);
    moe_gemm<2, HDIM, DDIM, 4><<<GGRID, 256, 0, stream>>>(
        h, wb2, nullptr, meta, tokp, y0, y1, y2, y3, nullptr, nullptr, 0);
    combine_kernel<4><<<NTOK, 256, 0, stream>>>(y0, y1, y2, y3, te, tw, pidx, b2, outF);
  } else {
    moe_gemm<1, DDIM, HDIM, 1><<<GGRID, 256, 0, stream>>>(
        xb, wb, b1, meta, tokp, h, h, h, h, nullptr, nullptr, 0);
    conv2_kernel<<<C2BLKS, 512, 0, stream>>>(w2, wb);
    moe_gemm<2, HDIM, DDIM, 2><<<GGRID, 256, 0, stream>>>(
        h, wb, nullptr, meta, tokp, y0, y1, y0, y1, nullptr, nullptr, 0);
    combine_kernel<2><<<NTOK, 256, 0, stream>>>(y0, y1, y0, y1, te, tw, pidx, b2, outF);
  }
}